// Round 1
// baseline (664.898 us; speedup 1.0000x reference)
//
#include <hip/hip_runtime.h>
#include <math.h>

// Problem constants (from reference): B=8, CIN=3, COUT=16, H=W=384
#define BQ   8
#define CIN  3
#define COUT 16
#define HW   (384 * 384)          // 147456 pixels per image
#define NPIX (BQ * HW)            // 1,179,648 pixels total
#define NELT ((double)NPIX * COUT) // 18,874,368 elements of v
#define MAX_ITERS 16              // while-loop upper bound (est. ~3-4 live iters)

struct Acc {
    double sum[MAX_ITERS + 1];    // sum|v| after pre-conv (idx 0) and each body iter
    int done;
};

// Block-wide sum (block = 256 threads = 4 waves of 64). Returns full sum on tid 0.
__device__ __forceinline__ float block_reduce_add(float v) {
    #pragma unroll
    for (int off = 32; off > 0; off >>= 1)
        v += __shfl_down(v, off, 64);
    __shared__ float red[4];
    int lane = threadIdx.x & 63;
    int wid  = threadIdx.x >> 6;
    if (lane == 0) red[wid] = v;
    __syncthreads();
    float r = 0.f;
    if (threadIdx.x == 0) r = red[0] + red[1] + red[2] + red[3];
    return r;
}

__global__ void k_init(Acc* a) {
    int t = threadIdx.x;
    if (t <= MAX_ITERS) a->sum[t] = 0.0;
    if (t == 0) a->done = 0;
}

// v = w_pre @ x + b_pre   (3 -> 16 channels), accumulate sum|v| into acc->sum[0]
__global__ __launch_bounds__(256) void k_pre(const float* __restrict__ x,
                                             const float* __restrict__ w,
                                             const float* __restrict__ bias,
                                             float* __restrict__ v,
                                             Acc* acc) {
    int p  = blockIdx.x * 256 + threadIdx.x;     // grid sized exactly NPIX/256
    int b  = p / HW;
    int hw = p - b * HW;

    const float* xb = x + (size_t)b * CIN * HW + hw;
    float xin[CIN];
    #pragma unroll
    for (int c = 0; c < CIN; ++c) xin[c] = xb[(size_t)c * HW];

    float* vb = v + (size_t)b * COUT * HW + hw;
    float s = 0.f;
    #pragma unroll
    for (int o = 0; o < COUT; ++o) {
        float t = bias[o];
        #pragma unroll
        for (int c = 0; c < CIN; ++c) t = fmaf(w[o * CIN + c], xin[c], t);
        vb[(size_t)o * HW] = t;
        s += fabsf(t);
    }
    float r = block_reduce_add(s);
    if (threadIdx.x == 0) atomicAdd(&acc->sum[0], (double)r);
}

// One while-loop body iteration, guarded by the device-side condition.
// v <- 10 * (w_loop @ tanh(w_shared @ v + b_shared) + b_loop), in place.
__global__ __launch_bounds__(256) void k_body(float* __restrict__ v,
                                              const float* __restrict__ ws,
                                              const float* __restrict__ bs,
                                              const float* __restrict__ wl,
                                              const float* __restrict__ bl,
                                              Acc* acc, int iter) {
    if (acc->done) return;                        // uniform: prior iter terminated
    double mean = acc->sum[iter - 1] / NELT;
    if (mean >= 3.0) {                            // while-cond false -> stop chain
        if (blockIdx.x == 0 && threadIdx.x == 0) acc->done = 1;
        return;
    }

    int p  = blockIdx.x * 256 + threadIdx.x;
    int b  = p / HW;
    int hw = p - b * HW;
    float* vb = v + (size_t)b * COUT * HW + hw;

    float vin[COUT];
    #pragma unroll
    for (int c = 0; c < COUT; ++c) vin[c] = vb[(size_t)c * HW];

    float t[COUT];
    #pragma unroll
    for (int o = 0; o < COUT; ++o) {
        float a = bs[o];
        #pragma unroll
        for (int c = 0; c < COUT; ++c) a = fmaf(ws[o * COUT + c], vin[c], a);
        t[o] = tanhf(a);
    }

    float s = 0.f;
    #pragma unroll
    for (int o = 0; o < COUT; ++o) {
        float a = bl[o];
        #pragma unroll
        for (int c = 0; c < COUT; ++c) a = fmaf(wl[o * COUT + c], t[c], a);
        a *= 10.f;
        vb[(size_t)o * HW] = a;
        s += fabsf(a);
    }
    float r = block_reduce_add(s);
    if (threadIdx.x == 0) atomicAdd(&acc->sum[iter], (double)r);
}

// out = w_shared @ v + b_shared, in place on d_out.
__global__ __launch_bounds__(256) void k_final(float* __restrict__ v,
                                               const float* __restrict__ ws,
                                               const float* __restrict__ bs) {
    int p  = blockIdx.x * 256 + threadIdx.x;
    int b  = p / HW;
    int hw = p - b * HW;
    float* vb = v + (size_t)b * COUT * HW + hw;

    float vin[COUT];
    #pragma unroll
    for (int c = 0; c < COUT; ++c) vin[c] = vb[(size_t)c * HW];

    #pragma unroll
    for (int o = 0; o < COUT; ++o) {
        float a = bs[o];
        #pragma unroll
        for (int c = 0; c < COUT; ++c) a = fmaf(ws[o * COUT + c], vin[c], a);
        vb[(size_t)o * HW] = a;
    }
}

extern "C" void kernel_launch(void* const* d_in, const int* in_sizes, int n_in,
                              void* d_out, int out_size, void* d_ws, size_t ws_size,
                              hipStream_t stream) {
    // setup_inputs() dict order: x, w_pre, b_pre, w_loop, b_loop, w_shared, b_shared
    const float* x        = (const float*)d_in[0];
    const float* w_pre    = (const float*)d_in[1];
    const float* b_pre    = (const float*)d_in[2];
    const float* w_loop   = (const float*)d_in[3];
    const float* b_loop   = (const float*)d_in[4];
    const float* w_shared = (const float*)d_in[5];
    const float* b_shared = (const float*)d_in[6];

    float* v = (float*)d_out;     // d_out doubles as the loop-state buffer (exact size)
    Acc* acc = (Acc*)d_ws;        // small accumulator struct in workspace

    const int blocks = NPIX / 256;  // 4608, exact

    k_init<<<1, 64, 0, stream>>>(acc);
    k_pre<<<blocks, 256, 0, stream>>>(x, w_pre, b_pre, v, acc);
    for (int i = 1; i <= MAX_ITERS; ++i)
        k_body<<<blocks, 256, 0, stream>>>(v, w_shared, b_shared,
                                           w_loop, b_loop, acc, i);
    k_final<<<blocks, 256, 0, stream>>>(v, w_shared, b_shared);
}